// Round 3
// baseline (226.101 us; speedup 1.0000x reference)
//
#include <hip/hip_runtime.h>

#define TOKENS 8192
#define IN_F   4096
#define OUT_F  4096

#define BM 128
#define BN 128
#define BK 64   // int8 elements per K-step (64 bytes/row, same byte geometry as m97)

using int4v = __attribute__((ext_vector_type(4))) int;
typedef __attribute__((address_space(3))) char       lds_char_t;
typedef const __attribute__((address_space(1))) char glob_char_t;

// ---------------- pack int32 -> int8 (values already in [-128,127]) ----------------
__global__ void pack_i32_to_i8(const int* __restrict__ src, int* __restrict__ dst, int n4) {
    int stride = gridDim.x * blockDim.x;
    for (int i = blockIdx.x * blockDim.x + threadIdx.x; i < n4; i += stride) {
        int4v v = ((const int4v*)src)[i];
        dst[i] = (v.x & 0xff) | ((v.y & 0xff) << 8) | ((v.z & 0xff) << 16) | (v.w << 24);
    }
}

// ---------------- main GEMM: C[m][n] = requant( sum_k A[m][k]*W[n][k] + bias[n] ) ----------------
// m97 structure: 128x128 tile, 4 waves (2x2), BK=64 int8, global_load_lds width 16, 2-barrier loop.
__global__ __launch_bounds__(256, 2) void qgemm_i8(
    const signed char* __restrict__ A,   // [M][K] int8
    const signed char* __restrict__ B,   // [N][K] int8 (weight, K contiguous -> B^T gemm)
    const int*   __restrict__ bias,      // [N]
    const float* __restrict__ wscale,    // [N]
    const float* __restrict__ p_si, const float* __restrict__ p_so, const float* __restrict__ p_zp,
    int* __restrict__ C)                 // harness reads output as int32
{
    constexpr int M = TOKENS, N = OUT_F, K = IN_F;
    constexpr int NBN = N / BN;  // 32

    __shared__ signed char lA[BM * BK];  // 8 KB
    __shared__ signed char lB[BN * BK];  // 8 KB

    // XCD-aware swizzle (nwg = 2048, %8 == 0 -> bijective)
    int nwg = gridDim.x;
    int bid = blockIdx.x;
    int swz = bid;
    if ((nwg & 7) == 0) {
        int cpx = nwg >> 3;
        swz = (bid & 7) * cpx + (bid >> 3);
    }
    int bm = swz / NBN;
    int bn = swz - bm * NBN;

    int t   = threadIdx.x;
    int wid = t >> 6;          // wave id 0..3
    int l   = t & 63;          // lane
    int lr  = l & 15;          // fragment row/col within 16
    int lk  = (l >> 4) * 16;   // k-byte offset of this lane's 16 int8
    int wr  = wid >> 1;        // wave row (0..1) -> 64 rows each
    int wc  = wid & 1;         // wave col (0..1) -> 64 cols each

    int4v acc[4][4] = {};      // 4x4 fragments of 16x16 i32

    const size_t a_base = (size_t)bm * BM * K;
    const size_t b_base = (size_t)bn * BN * K;

    // staging: tile = 8192 B, 256 thr x 16 B = 4096 B per issue -> 2 issues per tile
    int soff0 = t * 16;
    int row0 = soff0 >> 6, col0 = soff0 & 63;
    int soff1 = 4096 + t * 16;
    int row1 = soff1 >> 6, col1 = soff1 & 63;

    for (int k0 = 0; k0 < K; k0 += BK) {
        __builtin_amdgcn_global_load_lds((glob_char_t*)(A + a_base + (size_t)row0 * K + k0 + col0),
                                         (lds_char_t*)lA + wid * 1024,        16, 0, 0);
        __builtin_amdgcn_global_load_lds((glob_char_t*)(A + a_base + (size_t)row1 * K + k0 + col1),
                                         (lds_char_t*)lA + 4096 + wid * 1024, 16, 0, 0);
        __builtin_amdgcn_global_load_lds((glob_char_t*)(B + b_base + (size_t)row0 * K + k0 + col0),
                                         (lds_char_t*)lB + wid * 1024,        16, 0, 0);
        __builtin_amdgcn_global_load_lds((glob_char_t*)(B + b_base + (size_t)row1 * K + k0 + col1),
                                         (lds_char_t*)lB + 4096 + wid * 1024, 16, 0, 0);
        __syncthreads();  // compiler drains vmcnt(0) before s_barrier -> LDS tiles ready

        int4v a[4], b[4];
        #pragma unroll
        for (int i = 0; i < 4; ++i)
            a[i] = *(const int4v*)&lA[(wr * 64 + i * 16 + lr) * 64 + lk];
        #pragma unroll
        for (int j = 0; j < 4; ++j)
            b[j] = *(const int4v*)&lB[(wc * 64 + j * 16 + lr) * 64 + lk];

        #pragma unroll
        for (int i = 0; i < 4; ++i)
            #pragma unroll
            for (int j = 0; j < 4; ++j)
                acc[i][j] = __builtin_amdgcn_mfma_i32_16x16x64_i8(a[i], b[j], acc[i][j], 0, 0, 0);

        __syncthreads();
    }

    // epilogue: y = clip(rint(scale[n] * (acc + bias[n]) + zp), -128, 127), stored as int32
    float si = p_si[0], so = p_so[0], z = p_zp[0];
    float rs = si / so;
    int lg = l >> 4;  // lane group 0..3

    #pragma unroll
    for (int j = 0; j < 4; ++j) {
        int col = bn * BN + wc * 64 + j * 16 + lr;   // C/D: col = lane&15
        float sc = wscale[col] * rs;
        int   bs = bias[col];
        #pragma unroll
        for (int i = 0; i < 4; ++i) {
            int row = bm * BM + wr * 64 + i * 16 + lg * 4;  // C/D: row = (lane>>4)*4 + reg
            #pragma unroll
            for (int r = 0; r < 4; ++r) {
                float y = sc * (float)(acc[i][j][r] + bs) + z;
                y = rintf(y);  // round-half-even, matches jnp.round
                y = fminf(fmaxf(y, -128.0f), 127.0f);
                C[(size_t)(row + r) * N + col] = (int)y;
            }
        }
    }
}

// ---------------- fallback if workspace too small: naive but exact ----------------
__global__ void qgemm_naive(const int* __restrict__ qx, const int* __restrict__ qw,
                            const int* __restrict__ bias, const float* __restrict__ wscale,
                            const float* __restrict__ si, const float* __restrict__ so,
                            const float* __restrict__ zp, int* __restrict__ out) {
    int idx = blockIdx.x * blockDim.x + threadIdx.x;
    if (idx >= TOKENS * OUT_F) return;
    int row = idx / OUT_F, col = idx - row * OUT_F;
    const int4v* xa = (const int4v*)(qx + (size_t)row * IN_F);
    const int4v* wb = (const int4v*)(qw + (size_t)col * IN_F);
    int acc = 0;
    for (int k = 0; k < IN_F / 4; ++k) {
        int4v a = xa[k], b = wb[k];
        acc += a.x * b.x + a.y * b.y + a.z * b.z + a.w * b.w;
    }
    float y = wscale[col] * si[0] / so[0] * (float)(acc + bias[col]) + zp[0];
    y = fminf(fmaxf(rintf(y), -128.0f), 127.0f);
    out[idx] = (int)y;
}

extern "C" void kernel_launch(void* const* d_in, const int* in_sizes, int n_in,
                              void* d_out, int out_size, void* d_ws, size_t ws_size,
                              hipStream_t stream) {
    const int*   q_x    = (const int*)d_in[0];
    const int*   q_w    = (const int*)d_in[1];
    const int*   bias   = (const int*)d_in[2];
    const float* wscale = (const float*)d_in[3];
    const float* s_in   = (const float*)d_in[4];
    const float* s_out  = (const float*)d_in[5];
    const float* zp     = (const float*)d_in[6];
    int* out = (int*)d_out;

    const size_t needA = (size_t)TOKENS * IN_F;  // 32 MiB
    const size_t needB = (size_t)OUT_F * IN_F;   // 16 MiB

    if (ws_size >= needA + needB) {
        signed char* pA = (signed char*)d_ws;
        signed char* pB = pA + needA;
        pack_i32_to_i8<<<2048, 256, 0, stream>>>(q_x, (int*)pA, (int)(needA / 4));
        pack_i32_to_i8<<<1024, 256, 0, stream>>>(q_w, (int*)pB, (int)(needB / 4));
        int grid = (TOKENS / BM) * (OUT_F / BN);  // 64*32 = 2048
        qgemm_i8<<<grid, 256, 0, stream>>>(pA, pB, bias, wscale, s_in, s_out, zp, out);
    } else {
        int total = TOKENS * OUT_F;
        qgemm_naive<<<(total + 255) / 256, 256, 0, stream>>>(q_x, q_w, bias, wscale, s_in, s_out, zp, out);
    }
}

// Round 4
// 192.423 us; speedup vs baseline: 1.1750x; 1.1750x over previous
//
#include <hip/hip_runtime.h>

#define TOKENS 8192
#define IN_F   4096
#define OUT_F  4096

#define BM 256
#define BN 256
#define BK 64                       // bytes of K per tile (64 int8 = one mfma K-step)
#define NT (IN_F / BK)              // 64 K-tiles
#define SLOTS 4
#define SLOT_BYTES (2 * BM * BK)    // A half (16 KiB) + B half (16 KiB) = 32 KiB
#define A_OFF 0
#define B_OFF (BM * BK)             // 16384

using int4v = __attribute__((ext_vector_type(4))) int;
typedef __attribute__((address_space(3))) char       lds_char_t;
typedef const __attribute__((address_space(1))) char glob_char_t;

// ---------------- pack int32 -> int8 (values already in [-128,127]) ----------------
__global__ void pack_i32_to_i8(const int* __restrict__ src, int* __restrict__ dst, int n4) {
    int stride = gridDim.x * blockDim.x;
    for (int i = blockIdx.x * blockDim.x + threadIdx.x; i < n4; i += stride) {
        int4v v = ((const int4v*)src)[i];
        dst[i] = (v.x & 0xff) | ((v.y & 0xff) << 8) | ((v.z & 0xff) << 16) | (v.w << 24);
    }
}

// ---------------- 256x256 i8 GEMM, 4-slot LDS ring, counted vmcnt, T2 swizzle ----------------
// Ring discipline: group t reads slot t%4, stages tile t+3 into slot (t+3)%4 (disjoint).
// End of group t: vmcnt(8) guarantees tile t+1 landed (tiles t+2,t+3 = 8 loads/wave in flight).
// LDS swizzle: phys_byte = log_byte ^ (((row>>1)&3)<<4) -> 8-way bank conflict becomes 2-way (free).
// Applied on BOTH the pre-swizzled global source (staging) and the ds_read address (rule #21).
__global__ __launch_bounds__(512, 2) void qgemm_i8(
    const signed char* __restrict__ A,   // [M][K] int8
    const signed char* __restrict__ Bw,  // [N][K] int8
    const int*   __restrict__ bias,
    const float* __restrict__ wscale,
    const float* __restrict__ p_si, const float* __restrict__ p_so, const float* __restrict__ p_zp,
    int* __restrict__ C)
{
    constexpr int N = OUT_F, K = IN_F;
    constexpr int NBN = N / BN;  // 16

    __shared__ __align__(16) signed char smem[SLOTS * SLOT_BYTES];  // 128 KiB

    // XCD-aware swizzle (nwg = 512, %8 == 0 -> bijective)
    int nwg = gridDim.x;
    int bid = blockIdx.x;
    int swz = bid;
    if ((nwg & 7) == 0) {
        int cpx = nwg >> 3;
        swz = (bid & 7) * cpx + (bid >> 3);
    }
    int bm = swz / NBN;
    int bn = swz - bm * NBN;

    int t   = threadIdx.x;
    int wid = t >> 6;           // wave 0..7
    int l   = t & 63;
    int wr  = wid >> 2;         // 0..1 -> 128 rows
    int wc  = wid & 3;          // 0..3 -> 64 cols
    int lr  = l & 15;
    int lg  = l >> 4;
    int lk  = lg * 16;

    // ---- staging: per wave 2 A-instrs + 2 B-instrs per tile (16 rows x 64B each) ----
    // phys unit u = lane: row_in16 = l>>2, q_phys = l&3; inverse-swizzled logical q:
    int row16 = l >> 2;
    int q_log = (l & 3) ^ ((l >> 3) & 3);   // ((row>>1)&3) reduces to (l>>3)&3 (16-row blocks)

    const signed char* aSrc0 = A  + (size_t)(bm * BM + wid * 32 + row16) * K + q_log * 16;
    const signed char* aSrc1 = aSrc0 + (size_t)16 * K;
    const signed char* bSrc0 = Bw + (size_t)(bn * BN + wid * 32 + row16) * K + q_log * 16;
    const signed char* bSrc1 = bSrc0 + (size_t)16 * K;
    int ldsAo = A_OFF + wid * 2048;
    int ldsBo = B_OFF + wid * 2048;

    auto stageA = [&](int tt, int ss) {
        int k0 = tt * BK;
        __builtin_amdgcn_global_load_lds((glob_char_t*)(aSrc0 + k0),
                                         (lds_char_t*)smem + ss * SLOT_BYTES + ldsAo,        16, 0, 0);
        __builtin_amdgcn_global_load_lds((glob_char_t*)(aSrc1 + k0),
                                         (lds_char_t*)smem + ss * SLOT_BYTES + ldsAo + 1024, 16, 0, 0);
    };
    auto stageB = [&](int tt, int ss) {
        int k0 = tt * BK;
        __builtin_amdgcn_global_load_lds((glob_char_t*)(bSrc0 + k0),
                                         (lds_char_t*)smem + ss * SLOT_BYTES + ldsBo,        16, 0, 0);
        __builtin_amdgcn_global_load_lds((glob_char_t*)(bSrc1 + k0),
                                         (lds_char_t*)smem + ss * SLOT_BYTES + ldsBo + 1024, 16, 0, 0);
    };

    // ---- fragment read offsets (swizzled; xor mask is lane-constant) ----
    int xm   = ((lr >> 1) & 3) << 4;
    int aoff = (wr * 128 + lr) * 64 + (lk ^ xm);   // + m*1024
    int boff = (wc * 64  + lr) * 64 + (lk ^ xm);   // + n*1024

    int4v acc[8][4] = {};

    // ---- prologue: stage tiles 0,1,2 (12 loads/wave); tile 0 ready after vmcnt(8) ----
    stageA(0, 0); stageB(0, 0);
    stageA(1, 1); stageB(1, 1);
    stageA(2, 2); stageB(2, 2);
    asm volatile("s_waitcnt vmcnt(8)" ::: "memory");
    __builtin_amdgcn_s_barrier();

#define GROUP(s_, t3_, DO_STAGE_, VMASM_) do {                                            \
        const signed char* sA_ = smem + (s_) * SLOT_BYTES + A_OFF;                        \
        const signed char* sB_ = smem + (s_) * SLOT_BYTES + B_OFF;                        \
        int4v a_[8], b_[2];                                                               \
        _Pragma("unroll")                                                                 \
        for (int m = 0; m < 8; ++m) a_[m] = *(const int4v*)(sA_ + aoff + m * 1024);       \
        b_[0] = *(const int4v*)(sB_ + boff + 0 * 1024);                                   \
        b_[1] = *(const int4v*)(sB_ + boff + 1 * 1024);                                   \
        if (DO_STAGE_) stageA(t3_, (t3_) & 3);                                            \
        __builtin_amdgcn_s_barrier();                                                     \
        asm volatile("s_waitcnt lgkmcnt(0)");                                             \
        __builtin_amdgcn_s_setprio(1);                                                    \
        _Pragma("unroll")                                                                 \
        for (int m = 0; m < 8; ++m) {                                                     \
            acc[m][0] = __builtin_amdgcn_mfma_i32_16x16x64_i8(a_[m], b_[0], acc[m][0], 0, 0, 0); \
            acc[m][1] = __builtin_amdgcn_mfma_i32_16x16x64_i8(a_[m], b_[1], acc[m][1], 0, 0, 0); \
        }                                                                                 \
        __builtin_amdgcn_s_setprio(0);                                                    \
        __builtin_amdgcn_s_barrier();                                                     \
        b_[0] = *(const int4v*)(sB_ + boff + 2 * 1024);                                   \
        b_[1] = *(const int4v*)(sB_ + boff + 3 * 1024);                                   \
        if (DO_STAGE_) stageB(t3_, (t3_) & 3);                                            \
        __builtin_amdgcn_s_barrier();                                                     \
        asm volatile("s_waitcnt lgkmcnt(0)");                                             \
        __builtin_amdgcn_s_setprio(1);                                                    \
        _Pragma("unroll")                                                                 \
        for (int m = 0; m < 8; ++m) {                                                     \
            acc[m][2] = __builtin_amdgcn_mfma_i32_16x16x64_i8(a_[m], b_[0], acc[m][2], 0, 0, 0); \
            acc[m][3] = __builtin_amdgcn_mfma_i32_16x16x64_i8(a_[m], b_[1], acc[m][3], 0, 0, 0); \
        }                                                                                 \
        __builtin_amdgcn_s_setprio(0);                                                    \
        VMASM_;                                                                           \
        __builtin_amdgcn_s_barrier();                                                     \
    } while (0)

    // main loop: groups 0..60 stage tile t+3; counted vmcnt(8) — never drained to 0
    for (int tt = 0; tt < NT - 3; ++tt) {
        GROUP(tt & 3, tt + 3, true, asm volatile("s_waitcnt vmcnt(8)" ::: "memory"));
    }
    // tail: no staging left; drain progressively (61: need 62 landed; 62: need 63 landed)
    GROUP((NT - 3) & 3, 0, false, asm volatile("s_waitcnt vmcnt(4)" ::: "memory"));
    GROUP((NT - 2) & 3, 0, false, asm volatile("s_waitcnt vmcnt(0)" ::: "memory"));
    GROUP((NT - 1) & 3, 0, false, (void)0);
#undef GROUP

    // ---- epilogue: y = clip(rint(scale[n]*(acc+bias[n]) + zp)), stored as int32 ----
    float si = p_si[0], so = p_so[0], z = p_zp[0];
    float rs = si / so;

    #pragma unroll
    for (int n = 0; n < 4; ++n) {
        int col = bn * BN + wc * 64 + n * 16 + lr;
        float sc = wscale[col] * rs;
        int   bs = bias[col];
        #pragma unroll
        for (int m = 0; m < 8; ++m) {
            int row = bm * BM + wr * 128 + m * 16 + lg * 4;
            #pragma unroll
            for (int r = 0; r < 4; ++r) {
                float y = sc * (float)(acc[m][n][r] + bs) + z;
                y = rintf(y);
                y = fminf(fmaxf(y, -128.0f), 127.0f);
                C[(size_t)(row + r) * N + col] = (int)y;
            }
        }
    }
}

// ---------------- fallback if workspace too small: naive but exact ----------------
__global__ void qgemm_naive(const int* __restrict__ qx, const int* __restrict__ qw,
                            const int* __restrict__ bias, const float* __restrict__ wscale,
                            const float* __restrict__ si, const float* __restrict__ so,
                            const float* __restrict__ zp, int* __restrict__ out) {
    int idx = blockIdx.x * blockDim.x + threadIdx.x;
    if (idx >= TOKENS * OUT_F) return;
    int row = idx / OUT_F, col = idx - row * OUT_F;
    const int4v* xa = (const int4v*)(qx + (size_t)row * IN_F);
    const int4v* wb = (const int4v*)(qw + (size_t)col * IN_F);
    int acc = 0;
    for (int k = 0; k < IN_F / 4; ++k) {
        int4v a = xa[k], b = wb[k];
        acc += a.x * b.x + a.y * b.y + a.z * b.z + a.w * b.w;
    }
    float y = wscale[col] * si[0] / so[0] * (float)(acc + bias[col]) + zp[0];
    y = fminf(fmaxf(rintf(y), -128.0f), 127.0f);
    out[idx] = (int)y;
}

extern "C" void kernel_launch(void* const* d_in, const int* in_sizes, int n_in,
                              void* d_out, int out_size, void* d_ws, size_t ws_size,
                              hipStream_t stream) {
    const int*   q_x    = (const int*)d_in[0];
    const int*   q_w    = (const int*)d_in[1];
    const int*   bias   = (const int*)d_in[2];
    const float* wscale = (const float*)d_in[3];
    const float* s_in   = (const float*)d_in[4];
    const float* s_out  = (const float*)d_in[5];
    const float* zp     = (const float*)d_in[6];
    int* out = (int*)d_out;

    const size_t needA = (size_t)TOKENS * IN_F;  // 32 MiB
    const size_t needB = (size_t)OUT_F * IN_F;   // 16 MiB

    if (ws_size >= needA + needB) {
        signed char* pA = (signed char*)d_ws;
        signed char* pB = pA + needA;
        pack_i32_to_i8<<<2048, 256, 0, stream>>>(q_x, (int*)pA, (int)(needA / 4));
        pack_i32_to_i8<<<1024, 256, 0, stream>>>(q_w, (int*)pB, (int)(needB / 4));
        int grid = (TOKENS / BM) * (OUT_F / BN);  // 32*16 = 512
        qgemm_i8<<<grid, 512, 0, stream>>>(pA, pB, bias, wscale, s_in, s_out, zp, out);
    } else {
        int total = TOKENS * OUT_F;
        qgemm_naive<<<(total + 255) / 256, 256, 0, stream>>>(q_x, q_w, bias, wscale, s_in, s_out, zp, out);
    }
}

// Round 5
// 183.867 us; speedup vs baseline: 1.2297x; 1.0465x over previous
//
#include <hip/hip_runtime.h>

#define TOKENS 8192
#define IN_F   4096
#define OUT_F  4096

#define BM 256
#define BN 256
#define BKB 128              // K-bytes per tile (= 2 mfma K-steps of 64)
#define NT (IN_F / BKB)      // 32 K-tiles
#define NI (NT / 2)          // 16 outer iterations (2 tiles each)

using int4v = __attribute__((ext_vector_type(4))) int;
typedef __attribute__((address_space(3))) char       lds_char_t;
typedef const __attribute__((address_space(1))) char glob_char_t;

// ---------------- pack int32 -> int8 (values already in [-128,127]) ----------------
__global__ void pack_i32_to_i8(const int* __restrict__ src, int* __restrict__ dst, int n4) {
    int stride = gridDim.x * blockDim.x;
    for (int i = blockIdx.x * blockDim.x + threadIdx.x; i < n4; i += stride) {
        int4v v = ((const int4v*)src)[i];
        dst[i] = (v.x & 0xff) | ((v.y & 0xff) << 8) | ((v.z & 0xff) << 16) | (v.w << 24);
    }
}

// ---------------- 256x256 i8 GEMM, 8-phase schedule (m201 port), BK=128B ----------------
// buf0 (LDS 0..65535) holds even K-tiles, buf1 (65536..131071) odd K-tiles.
// Per phase: {ds_read quadrant frags | stage 1 half-tile (2 gload_lds)} -> barrier ->
// lgkmcnt(0) -> setprio(1) -> 16 MFMA -> setprio(0) -> [vmcnt(4) @ P4,P8] -> barrier.
// Stagger: P1,P2 stage (2i+1).B ; P3,P4 stage (2i+2).A ; P5,P6 stage (2i+2).B ;
//          P7,P8 stage (2i+3).A.  Every region's reads complete >=1 barrier before
//          its overwrite issues; every staged load gets >=3 phases before first read,
//          and the vmcnt(4) that guards it is >=4 phases after issue.
// LDS swizzle: byte col ^= ((row&7)<<4) within each 128-B row (16B granule preserved);
// inverse applied on the per-lane global source (rule #21 both-sides).
__global__ __launch_bounds__(512, 2) void qgemm_i8(
    const signed char* __restrict__ A,   // [M][K] int8
    const signed char* __restrict__ Bw,  // [N][K] int8
    const int*   __restrict__ bias,
    const float* __restrict__ wscale,
    const float* __restrict__ p_si, const float* __restrict__ p_so, const float* __restrict__ p_zp,
    int* __restrict__ C)
{
    constexpr int N = OUT_F, K = IN_F;
    constexpr int NBN = N / BN;  // 16

    __shared__ __align__(16) signed char smem[131072];

    // XCD-aware swizzle (nwg = 512, %8 == 0 -> bijective)
    int nwg = gridDim.x, bid = blockIdx.x, swz = bid;
    if ((nwg & 7) == 0) { int cpx = nwg >> 3; swz = (bid & 7) * cpx + (bid >> 3); }
    int bm = swz / NBN, bn = swz - bm * NBN;

    const int t = threadIdx.x, wid = t >> 6, l = t & 63;
    const int wr = wid >> 2, wc = wid & 3, lr = l & 15, lg = l >> 4;

    // ds_read offsets: frag (row, kk): byte = row*128 + ((kk*4+lg)^(lr&7))<<4
    const int k0off = ((lg       ^ (lr & 7)) << 4);
    const int k1off = (((4 + lg) ^ (lr & 7)) << 4);
    const int arow = (wr * 128 + lr) * 128;  // + m*2048
    const int brow = (wc * 64  + lr) * 128;  // + n*2048

    // staging: thread t writes LDS-linear o = e*8192 + t*16 within a half-tile
    // (row = e*64 + t>>3, col16 = t&7); inverse-swizzled global column:
    const int srow = t >> 3;                                  // 0..63
    const int scol = (((t & 7) ^ ((t >> 3) & 7)) << 4);
    const signed char* gApl = A  + (size_t)(bm * BM + srow) * K + scol;
    const signed char* gBpl = Bw + (size_t)(bn * BN + srow) * K + scol;

#define STA(bufOff_, h_, tt_) do {                                                                 \
    __builtin_amdgcn_global_load_lds((glob_char_t*)(gApl + (size_t)((h_)*128      ) * K + (tt_)*BKB), \
        (lds_char_t*)smem + (bufOff_) + (h_)*16384 +        wid*1024, 16, 0, 0);                   \
    __builtin_amdgcn_global_load_lds((glob_char_t*)(gApl + (size_t)((h_)*128 + 64 ) * K + (tt_)*BKB), \
        (lds_char_t*)smem + (bufOff_) + (h_)*16384 + 8192 + wid*1024, 16, 0, 0);                   \
} while (0)
#define STB(bufOff_, h_, tt_) do {                                                                 \
    __builtin_amdgcn_global_load_lds((glob_char_t*)(gBpl + (size_t)((h_)*128      ) * K + (tt_)*BKB), \
        (lds_char_t*)smem + (bufOff_) + 32768 + (h_)*16384 +        wid*1024, 16, 0, 0);           \
    __builtin_amdgcn_global_load_lds((glob_char_t*)(gBpl + (size_t)((h_)*128 + 64 ) * K + (tt_)*BKB), \
        (lds_char_t*)smem + (bufOff_) + 32768 + (h_)*16384 + 8192 + wid*1024, 16, 0, 0);           \
} while (0)

#define LDA4(bufOff_, mb_) do { _Pragma("unroll") for (int mm = 0; mm < 4; ++mm) {                 \
    a[(mb_)+mm][0] = *(const int4v*)(smem + (bufOff_) + arow + ((mb_)+mm)*2048 + k0off);           \
    a[(mb_)+mm][1] = *(const int4v*)(smem + (bufOff_) + arow + ((mb_)+mm)*2048 + k1off); } } while (0)
#define LDB2(bufOff_, nb_) do { _Pragma("unroll") for (int nn = 0; nn < 2; ++nn) {                 \
    b[(nb_)+nn][0] = *(const int4v*)(smem + (bufOff_) + 32768 + brow + ((nb_)+nn)*2048 + k0off);   \
    b[(nb_)+nn][1] = *(const int4v*)(smem + (bufOff_) + 32768 + brow + ((nb_)+nn)*2048 + k1off); } } while (0)

#define MF(mb_, nb_) do { _Pragma("unroll") for (int kk = 0; kk < 2; ++kk)                         \
    _Pragma("unroll") for (int mm = 0; mm < 4; ++mm)                                               \
    _Pragma("unroll") for (int nn = 0; nn < 2; ++nn)                                               \
        acc[(mb_)+mm][(nb_)+nn] = __builtin_amdgcn_mfma_i32_16x16x64_i8(                           \
            a[(mb_)+mm][kk], b[(nb_)+nn][kk], acc[(mb_)+mm][(nb_)+nn], 0, 0, 0); } while (0)

#define PH_MID() do { __builtin_amdgcn_s_barrier();                                                \
    asm volatile("s_waitcnt lgkmcnt(0)"); __builtin_amdgcn_s_setprio(1); } while (0)
#define PH_END() do { __builtin_amdgcn_s_setprio(0); __builtin_amdgcn_s_barrier(); } while (0)

    int4v acc[8][4] = {};
    int4v a[8][2], b[4][2];

    // ---- prologue: tile0 A+B -> buf0, tile1 A -> buf1 (12 loads); tile0 landed @ vmcnt(4)
    STA(0, 0, 0); STA(0, 1, 0); STB(0, 0, 0); STB(0, 1, 0);
    STA(65536, 0, 1); STA(65536, 1, 1);
    asm volatile("s_waitcnt vmcnt(4)" ::: "memory");
    __builtin_amdgcn_s_barrier();

#define ITER(i_, FULL_) do {                                                                       \
    const int t1 = 2*(i_)+1, t2 = 2*(i_)+2, t3 = 2*(i_)+3;                                         \
    /* P1 */ LDA4(0, 0); LDB2(0, 0); STB(65536, 0, t1);                                            \
    PH_MID(); MF(0, 0); PH_END();                                                                  \
    /* P2 */ LDA4(0, 4); STB(65536, 1, t1);                                                        \
    PH_MID(); MF(4, 0); PH_END();                                                                  \
    /* P3 */ LDB2(0, 2); if (FULL_) STA(0, 0, t2);                                                 \
    PH_MID(); MF(0, 2); PH_END();                                                                  \
    /* P4 */ if (FULL_) STA(0, 1, t2);                                                             \
    PH_MID(); MF(4, 2); __builtin_amdgcn_s_setprio(0);                                             \
    if (FULL_) { asm volatile("s_waitcnt vmcnt(4)" ::: "memory"); }                                \
    else       { asm volatile("s_waitcnt vmcnt(0)" ::: "memory"); }                                \
    __builtin_amdgcn_s_barrier();                                                                  \
    /* P5 */ LDA4(65536, 0); LDB2(65536, 0); if (FULL_) STB(0, 0, t2);                             \
    PH_MID(); MF(0, 0); PH_END();                                                                  \
    /* P6 */ LDA4(65536, 4); if (FULL_) STB(0, 1, t2);                                             \
    PH_MID(); MF(4, 0); PH_END();                                                                  \
    /* P7 */ LDB2(65536, 2); if (FULL_) STA(65536, 0, t3);                                         \
    PH_MID(); MF(0, 2); PH_END();                                                                  \
    /* P8 */ if (FULL_) STA(65536, 1, t3);                                                         \
    PH_MID(); MF(4, 2); __builtin_amdgcn_s_setprio(0);                                             \
    if (FULL_) { asm volatile("s_waitcnt vmcnt(4)" ::: "memory"); }                                \
    __builtin_amdgcn_s_barrier();                                                                  \
} while (0)

    for (int i = 0; i < NI - 1; ++i) ITER(i, 1);
    ITER(NI - 1, 0);

#undef ITER
#undef PH_END
#undef PH_MID
#undef MF
#undef LDB2
#undef LDA4
#undef STB
#undef STA

    // ---- epilogue: y = clip(rint(scale[n]*(acc+bias[n]) + zp)), stored as int32 ----
    float si = p_si[0], so = p_so[0], z = p_zp[0];
    float rs = si / so;

    #pragma unroll
    for (int n = 0; n < 4; ++n) {
        int col = bn * BN + wc * 64 + n * 16 + lr;
        float sc = wscale[col] * rs;
        int   bs = bias[col];
        #pragma unroll
        for (int m = 0; m < 8; ++m) {
            int row = bm * BM + wr * 128 + m * 16 + lg * 4;
            #pragma unroll
            for (int r = 0; r < 4; ++r) {
                float y = sc * (float)(acc[m][n][r] + bs) + z;
                y = rintf(y);
                y = fminf(fmaxf(y, -128.0f), 127.0f);
                C[(size_t)(row + r) * N + col] = (int)y;
            }
        }
    }
}

// ---------------- fallback if workspace too small: naive but exact ----------------
__global__ void qgemm_naive(const int* __restrict__ qx, const int* __restrict__ qw,
                            const int* __restrict__ bias, const float* __restrict__ wscale,
                            const float* __restrict__ si, const float* __restrict__ so,
                            const float* __restrict__ zp, int* __restrict__ out) {
    int idx = blockIdx.x * blockDim.x + threadIdx.x;
    if (idx >= TOKENS * OUT_F) return;
    int row = idx / OUT_F, col = idx - row * OUT_F;
    const int4v* xa = (const int4v*)(qx + (size_t)row * IN_F);
    const int4v* wb = (const int4v*)(qw + (size_t)col * IN_F);
    int acc = 0;
    for (int k = 0; k < IN_F / 4; ++k) {
        int4v a = xa[k], b = wb[k];
        acc += a.x * b.x + a.y * b.y + a.z * b.z + a.w * b.w;
    }
    float y = wscale[col] * si[0] / so[0] * (float)(acc + bias[col]) + zp[0];
    y = fminf(fmaxf(rintf(y), -128.0f), 127.0f);
    out[idx] = (int)y;
}

extern "C" void kernel_launch(void* const* d_in, const int* in_sizes, int n_in,
                              void* d_out, int out_size, void* d_ws, size_t ws_size,
                              hipStream_t stream) {
    const int*   q_x    = (const int*)d_in[0];
    const int*   q_w    = (const int*)d_in[1];
    const int*   bias   = (const int*)d_in[2];
    const float* wscale = (const float*)d_in[3];
    const float* s_in   = (const float*)d_in[4];
    const float* s_out  = (const float*)d_in[5];
    const float* zp     = (const float*)d_in[6];
    int* out = (int*)d_out;

    const size_t needA = (size_t)TOKENS * IN_F;  // 32 MiB
    const size_t needB = (size_t)OUT_F * IN_F;   // 16 MiB

    if (ws_size >= needA + needB) {
        signed char* pA = (signed char*)d_ws;
        signed char* pB = pA + needA;
        pack_i32_to_i8<<<2048, 256, 0, stream>>>(q_x, (int*)pA, (int)(needA / 4));
        pack_i32_to_i8<<<1024, 256, 0, stream>>>(q_w, (int*)pB, (int)(needB / 4));
        int grid = (TOKENS / BM) * (OUT_F / BN);  // 32*16 = 512
        qgemm_i8<<<grid, 512, 0, stream>>>(pA, pB, bias, wscale, s_in, s_out, zp, out);
    } else {
        int total = TOKENS * OUT_F;
        qgemm_naive<<<(total + 255) / 256, 256, 0, stream>>>(q_x, q_w, bias, wscale, s_in, s_out, zp, out);
    }
}

// Round 6
// 183.839 us; speedup vs baseline: 1.2299x; 1.0002x over previous
//
#include <hip/hip_runtime.h>

#define TOKENS 8192
#define IN_F   4096
#define OUT_F  4096

#define BM 256
#define BN 256
#define BKB 128              // K-bytes per tile (= 2 mfma K-steps of 64)
#define NT (IN_F / BKB)      // 32 K-tiles
#define NI (NT / 2)          // 16 outer iterations (2 tiles each)

using int4v = __attribute__((ext_vector_type(4))) int;
typedef __attribute__((address_space(3))) char       lds_char_t;
typedef const __attribute__((address_space(1))) char glob_char_t;

// ---------------- pack int32 -> int8 (values already in [-128,127]) ----------------
__global__ void pack_i32_to_i8(const int* __restrict__ src, int* __restrict__ dst, int n4) {
    int stride = gridDim.x * blockDim.x;
    for (int i = blockIdx.x * blockDim.x + threadIdx.x; i < n4; i += stride) {
        int4v v = ((const int4v*)src)[i];
        dst[i] = (v.x & 0xff) | ((v.y & 0xff) << 8) | ((v.z & 0xff) << 16) | (v.w << 24);
    }
}

// ---------------- 256x256 i8 GEMM, 8-phase schedule, BK=128B ----------------
// Same staging schedule / vmcnt(4) / swizzles as R4 (region lifetimes verified).
// Change vs R4: NO forced lgkmcnt(0) — ds_reads are plain loads consumed by this
// phase's MFMAs; the compiler emits counted lgkmcnt waits so the LDS drain tail
// overlaps the MFMA burst (the 660 cy/phase serial stall R4's drain caused).
// Race safety: every read completes before its consuming MFMA, which precedes the
// phase END barrier; any overwrite of that region is staged >=1 barrier later.
// vmcnt asm ("memory") pins reads from hoisting above staging-landing guarantees.
__global__ __launch_bounds__(512, 2) void qgemm_i8(
    const signed char* __restrict__ A,   // [M][K] int8
    const signed char* __restrict__ Bw,  // [N][K] int8
    const int*   __restrict__ bias,
    const float* __restrict__ wscale,
    const float* __restrict__ p_si, const float* __restrict__ p_so, const float* __restrict__ p_zp,
    int* __restrict__ C)
{
    constexpr int N = OUT_F, K = IN_F;
    constexpr int NBN = N / BN;  // 16

    __shared__ __align__(16) signed char smem[131072];

    // XCD-aware swizzle (nwg = 512, %8 == 0 -> bijective)
    int nwg = gridDim.x, bid = blockIdx.x, swz = bid;
    if ((nwg & 7) == 0) { int cpx = nwg >> 3; swz = (bid & 7) * cpx + (bid >> 3); }
    int bm = swz / NBN, bn = swz - bm * NBN;

    const int t = threadIdx.x, wid = t >> 6, l = t & 63;
    const int wr = wid >> 2, wc = wid & 3, lr = l & 15, lg = l >> 4;

    // ds_read offsets: frag (row, kk): byte = row*128 + ((kk*4+lg)^(lr&7))<<4
    const int k0off = ((lg       ^ (lr & 7)) << 4);
    const int k1off = (((4 + lg) ^ (lr & 7)) << 4);
    const int arow = (wr * 128 + lr) * 128;  // + m*2048
    const int brow = (wc * 64  + lr) * 128;  // + n*2048

    // staging: thread t writes LDS-linear o = e*8192 + t*16 within a half-tile
    // (row = e*64 + t>>3, col16 = t&7); inverse-swizzled global column:
    const int srow = t >> 3;                                  // 0..63
    const int scol = (((t & 7) ^ ((t >> 3) & 7)) << 4);
    const signed char* gApl = A  + (size_t)(bm * BM + srow) * K + scol;
    const signed char* gBpl = Bw + (size_t)(bn * BN + srow) * K + scol;

#define STA(bufOff_, h_, tt_) do {                                                                 \
    __builtin_amdgcn_global_load_lds((glob_char_t*)(gApl + (size_t)((h_)*128      ) * K + (tt_)*BKB), \
        (lds_char_t*)smem + (bufOff_) + (h_)*16384 +        wid*1024, 16, 0, 0);                   \
    __builtin_amdgcn_global_load_lds((glob_char_t*)(gApl + (size_t)((h_)*128 + 64 ) * K + (tt_)*BKB), \
        (lds_char_t*)smem + (bufOff_) + (h_)*16384 + 8192 + wid*1024, 16, 0, 0);                   \
} while (0)
#define STB(bufOff_, h_, tt_) do {                                                                 \
    __builtin_amdgcn_global_load_lds((glob_char_t*)(gBpl + (size_t)((h_)*128      ) * K + (tt_)*BKB), \
        (lds_char_t*)smem + (bufOff_) + 32768 + (h_)*16384 +        wid*1024, 16, 0, 0);           \
    __builtin_amdgcn_global_load_lds((glob_char_t*)(gBpl + (size_t)((h_)*128 + 64 ) * K + (tt_)*BKB), \
        (lds_char_t*)smem + (bufOff_) + 32768 + (h_)*16384 + 8192 + wid*1024, 16, 0, 0);           \
} while (0)

#define LDA4(bufOff_, mb_) do { _Pragma("unroll") for (int mm = 0; mm < 4; ++mm) {                 \
    a[(mb_)+mm][0] = *(const int4v*)(smem + (bufOff_) + arow + ((mb_)+mm)*2048 + k0off);           \
    a[(mb_)+mm][1] = *(const int4v*)(smem + (bufOff_) + arow + ((mb_)+mm)*2048 + k1off); } } while (0)
#define LDB2(bufOff_, nb_) do { _Pragma("unroll") for (int nn = 0; nn < 2; ++nn) {                 \
    b[(nb_)+nn][0] = *(const int4v*)(smem + (bufOff_) + 32768 + brow + ((nb_)+nn)*2048 + k0off);   \
    b[(nb_)+nn][1] = *(const int4v*)(smem + (bufOff_) + 32768 + brow + ((nb_)+nn)*2048 + k1off); } } while (0)

#define MF(mb_, nb_) do { _Pragma("unroll") for (int kk = 0; kk < 2; ++kk)                         \
    _Pragma("unroll") for (int mm = 0; mm < 4; ++mm)                                               \
    _Pragma("unroll") for (int nn = 0; nn < 2; ++nn)                                               \
        acc[(mb_)+mm][(nb_)+nn] = __builtin_amdgcn_mfma_i32_16x16x64_i8(                           \
            a[(mb_)+mm][kk], b[(nb_)+nn][kk], acc[(mb_)+mm][(nb_)+nn], 0, 0, 0); } while (0)

// counted-wait phase: barrier, setprio, MFMA (compiler inserts lgkmcnt(N) per use)
#define PH_MID() do { __builtin_amdgcn_s_barrier(); __builtin_amdgcn_s_setprio(1); } while (0)
#define PH_END() do { __builtin_amdgcn_s_setprio(0); __builtin_amdgcn_s_barrier(); } while (0)

    int4v acc[8][4] = {};
    int4v a[8][2], b[4][2];

    // ---- prologue: tile0 A+B -> buf0, tile1 A -> buf1 (12 loads); tile0 landed @ vmcnt(4)
    STA(0, 0, 0); STA(0, 1, 0); STB(0, 0, 0); STB(0, 1, 0);
    STA(65536, 0, 1); STA(65536, 1, 1);
    asm volatile("s_waitcnt vmcnt(4)" ::: "memory");
    __builtin_amdgcn_s_barrier();

#define ITER(i_, FULL_) do {                                                                       \
    const int t1 = 2*(i_)+1, t2 = 2*(i_)+2, t3 = 2*(i_)+3;                                         \
    /* P1 */ LDB2(0, 0); LDA4(0, 0); STB(65536, 0, t1);                                            \
    PH_MID(); MF(0, 0); PH_END();                                                                  \
    /* P2 */ LDA4(0, 4); STB(65536, 1, t1);                                                        \
    PH_MID(); MF(4, 0); PH_END();                                                                  \
    /* P3 */ LDB2(0, 2); if (FULL_) STA(0, 0, t2);                                                 \
    PH_MID(); MF(0, 2); PH_END();                                                                  \
    /* P4 */ if (FULL_) STA(0, 1, t2);                                                             \
    PH_MID(); MF(4, 2); __builtin_amdgcn_s_setprio(0);                                             \
    if (FULL_) { asm volatile("s_waitcnt vmcnt(4)" ::: "memory"); }                                \
    else       { asm volatile("s_waitcnt vmcnt(0)" ::: "memory"); }                                \
    __builtin_amdgcn_s_barrier();                                                                  \
    /* P5 */ LDB2(65536, 0); LDA4(65536, 0); if (FULL_) STB(0, 0, t2);                             \
    PH_MID(); MF(0, 0); PH_END();                                                                  \
    /* P6 */ LDA4(65536, 4); if (FULL_) STB(0, 1, t2);                                             \
    PH_MID(); MF(4, 0); PH_END();                                                                  \
    /* P7 */ LDB2(65536, 2); if (FULL_) STA(65536, 0, t3);                                         \
    PH_MID(); MF(0, 2); PH_END();                                                                  \
    /* P8 */ if (FULL_) STA(65536, 1, t3);                                                         \
    PH_MID(); MF(4, 2); __builtin_amdgcn_s_setprio(0);                                             \
    if (FULL_) { asm volatile("s_waitcnt vmcnt(4)" ::: "memory"); }                                \
    __builtin_amdgcn_s_barrier();                                                                  \
} while (0)

    for (int i = 0; i < NI - 1; ++i) ITER(i, 1);
    ITER(NI - 1, 0);

#undef ITER
#undef PH_END
#undef PH_MID
#undef MF
#undef LDB2
#undef LDA4
#undef STB
#undef STA

    // ---- epilogue: y = clip(rint(scale[n]*(acc+bias[n]) + zp)), stored as int32 ----
    float si = p_si[0], so = p_so[0], z = p_zp[0];
    float rs = si / so;

    #pragma unroll
    for (int n = 0; n < 4; ++n) {
        int col = bn * BN + wc * 64 + n * 16 + lr;
        float sc = wscale[col] * rs;
        int   bs = bias[col];
        #pragma unroll
        for (int m = 0; m < 8; ++m) {
            int row = bm * BM + wr * 128 + m * 16 + lg * 4;
            #pragma unroll
            for (int r = 0; r < 4; ++r) {
                float y = sc * (float)(acc[m][n][r] + bs) + z;
                y = rintf(y);
                y = fminf(fmaxf(y, -128.0f), 127.0f);
                C[(size_t)(row + r) * N + col] = (int)y;
            }
        }
    }
}

// ---------------- fallback if workspace too small: naive but exact ----------------
__global__ void qgemm_naive(const int* __restrict__ qx, const int* __restrict__ qw,
                            const int* __restrict__ bias, const float* __restrict__ wscale,
                            const float* __restrict__ si, const float* __restrict__ so,
                            const float* __restrict__ zp, int* __restrict__ out) {
    int idx = blockIdx.x * blockDim.x + threadIdx.x;
    if (idx >= TOKENS * OUT_F) return;
    int row = idx / OUT_F, col = idx - row * OUT_F;
    const int4v* xa = (const int4v*)(qx + (size_t)row * IN_F);
    const int4v* wb = (const int4v*)(qw + (size_t)col * IN_F);
    int acc = 0;
    for (int k = 0; k < IN_F / 4; ++k) {
        int4v a = xa[k], b = wb[k];
        acc += a.x * b.x + a.y * b.y + a.z * b.z + a.w * b.w;
    }
    float y = wscale[col] * si[0] / so[0] * (float)(acc + bias[col]) + zp[0];
    y = fminf(fmaxf(rintf(y), -128.0f), 127.0f);
    out[idx] = (int)y;
}

extern "C" void kernel_launch(void* const* d_in, const int* in_sizes, int n_in,
                              void* d_out, int out_size, void* d_ws, size_t ws_size,
                              hipStream_t stream) {
    const int*   q_x    = (const int*)d_in[0];
    const int*   q_w    = (const int*)d_in[1];
    const int*   bias   = (const int*)d_in[2];
    const float* wscale = (const float*)d_in[3];
    const float* s_in   = (const float*)d_in[4];
    const float* s_out  = (const float*)d_in[5];
    const float* zp     = (const float*)d_in[6];
    int* out = (int*)d_out;

    const size_t needA = (size_t)TOKENS * IN_F;  // 32 MiB
    const size_t needB = (size_t)OUT_F * IN_F;   // 16 MiB

    if (ws_size >= needA + needB) {
        signed char* pA = (signed char*)d_ws;
        signed char* pB = pA + needA;
        pack_i32_to_i8<<<2048, 256, 0, stream>>>(q_x, (int*)pA, (int)(needA / 4));
        pack_i32_to_i8<<<1024, 256, 0, stream>>>(q_w, (int*)pB, (int)(needB / 4));
        int grid = (TOKENS / BM) * (OUT_F / BN);  // 32*16 = 512
        qgemm_i8<<<grid, 512, 0, stream>>>(pA, pB, bias, wscale, s_in, s_out, zp, out);
    } else {
        int total = TOKENS * OUT_F;
        qgemm_naive<<<(total + 255) / 256, 256, 0, stream>>>(q_x, q_w, bias, wscale, s_in, s_out, zp, out);
    }
}

// Round 7
// 181.572 us; speedup vs baseline: 1.2452x; 1.0125x over previous
//
#include <hip/hip_runtime.h>

#define TOKENS 8192
#define IN_F   4096
#define OUT_F  4096

#define BM 256
#define BN 256
#define BKB 128              // K-bytes per tile (= 2 mfma K-steps of 64)
#define NT (IN_F / BKB)      // 32 K-tiles
#define NI (NT / 2)          // 16 outer iterations (2 tiles each)

using int4v = __attribute__((ext_vector_type(4))) int;
typedef __attribute__((address_space(3))) char       lds_char_t;
typedef const __attribute__((address_space(1))) char glob_char_t;

// ---------------- pack int32 -> int8 (values already in [-128,127]) ----------------
__global__ void pack_i32_to_i8(const int* __restrict__ src, int* __restrict__ dst, int n4) {
    int stride = gridDim.x * blockDim.x;
    for (int i = blockIdx.x * blockDim.x + threadIdx.x; i < n4; i += stride) {
        int4v v = ((const int4v*)src)[i];
        dst[i] = (v.x & 0xff) | ((v.y & 0xff) << 8) | ((v.z & 0xff) << 16) | (v.w << 24);
    }
}

// ---------------- 256x256 i8 GEMM, 8-phase pipelined schedule, BK=128B ----------------
// vs R6: reads SHIFTED ONE PHASE EARLY — phase p issues the ds_reads consumed by
// phase p+1's MFMA, so the LDS drain overlaps phase p's MFMA + barrier wait
// (R6's phase = drain(1150cy) then MFMA(653cy), serialized => 1313cy measured).
// Register liveness: the a[8][2]/b[4][2] rotation has each frag's last consumer
// >=1 phase (program order) before the shifted load issue -> NO double buffering.
// Confirmations: vmcnt(2) at end-P3 (confirms buf1 tile 2i+1: A staged prev P7/P8,
// B staged P1/P2) and end-P7 (confirms buf0 tile 2i+2: staged P3..P6). Reads of a
// region are issued only after the barrier FOLLOWING its confirmation vmcnt.
// Overwrite safety: each LDS region's last ds_read is consumed by an MFMA >=1
// barrier before the overwriting stage is issued. One barrier per phase.
__global__ __launch_bounds__(512, 2) void qgemm_i8(
    const signed char* __restrict__ A,   // [M][K] int8
    const signed char* __restrict__ Bw,  // [N][K] int8
    const int*   __restrict__ bias,
    const float* __restrict__ wscale,
    const float* __restrict__ p_si, const float* __restrict__ p_so, const float* __restrict__ p_zp,
    int* __restrict__ C)
{
    constexpr int N = OUT_F, K = IN_F;
    constexpr int NBN = N / BN;  // 16

    __shared__ __align__(16) signed char smem[131072];

    // XCD-aware swizzle (nwg = 512, %8 == 0 -> bijective)
    int nwg = gridDim.x, bid = blockIdx.x, swz = bid;
    if ((nwg & 7) == 0) { int cpx = nwg >> 3; swz = (bid & 7) * cpx + (bid >> 3); }
    int bm = swz / NBN, bn = swz - bm * NBN;

    const int t = threadIdx.x, wid = t >> 6, l = t & 63;
    const int wr = wid >> 2, wc = wid & 3, lr = l & 15, lg = l >> 4;

    // ds_read offsets: frag (row, kk): byte = row*128 + ((kk*4+lg)^(lr&7))<<4
    const int k0off = ((lg       ^ (lr & 7)) << 4);
    const int k1off = (((4 + lg) ^ (lr & 7)) << 4);
    const int arow = (wr * 128 + lr) * 128;  // + m*2048
    const int brow = (wc * 64  + lr) * 128;  // + n*2048

    // staging: thread t writes LDS-linear o = e*8192 + t*16 within a half-tile
    // (row = e*64 + t>>3, col16 = t&7); inverse-swizzled global column:
    const int srow = t >> 3;                                  // 0..63
    const int scol = (((t & 7) ^ ((t >> 3) & 7)) << 4);
    const signed char* gApl = A  + (size_t)(bm * BM + srow) * K + scol;
    const signed char* gBpl = Bw + (size_t)(bn * BN + srow) * K + scol;

#define STA(bufOff_, h_, tt_) do {                                                                 \
    __builtin_amdgcn_global_load_lds((glob_char_t*)(gApl + (size_t)((h_)*128      ) * K + (tt_)*BKB), \
        (lds_char_t*)smem + (bufOff_) + (h_)*16384 +        wid*1024, 16, 0, 0);                   \
    __builtin_amdgcn_global_load_lds((glob_char_t*)(gApl + (size_t)((h_)*128 + 64 ) * K + (tt_)*BKB), \
        (lds_char_t*)smem + (bufOff_) + (h_)*16384 + 8192 + wid*1024, 16, 0, 0);                   \
} while (0)
#define STB(bufOff_, h_, tt_) do {                                                                 \
    __builtin_amdgcn_global_load_lds((glob_char_t*)(gBpl + (size_t)((h_)*128      ) * K + (tt_)*BKB), \
        (lds_char_t*)smem + (bufOff_) + 32768 + (h_)*16384 +        wid*1024, 16, 0, 0);           \
    __builtin_amdgcn_global_load_lds((glob_char_t*)(gBpl + (size_t)((h_)*128 + 64 ) * K + (tt_)*BKB), \
        (lds_char_t*)smem + (bufOff_) + 32768 + (h_)*16384 + 8192 + wid*1024, 16, 0, 0);           \
} while (0)

#define LDA4(bufOff_, mb_) do { _Pragma("unroll") for (int mm = 0; mm < 4; ++mm) {                 \
    a[(mb_)+mm][0] = *(const int4v*)(smem + (bufOff_) + arow + ((mb_)+mm)*2048 + k0off);           \
    a[(mb_)+mm][1] = *(const int4v*)(smem + (bufOff_) + arow + ((mb_)+mm)*2048 + k1off); } } while (0)
#define LDB2(bufOff_, nb_) do { _Pragma("unroll") for (int nn = 0; nn < 2; ++nn) {                 \
    b[(nb_)+nn][0] = *(const int4v*)(smem + (bufOff_) + 32768 + brow + ((nb_)+nn)*2048 + k0off);   \
    b[(nb_)+nn][1] = *(const int4v*)(smem + (bufOff_) + 32768 + brow + ((nb_)+nn)*2048 + k1off); } } while (0)

#define MF(mb_, nb_) do { _Pragma("unroll") for (int kk = 0; kk < 2; ++kk)                         \
    _Pragma("unroll") for (int mm = 0; mm < 4; ++mm)                                               \
    _Pragma("unroll") for (int nn = 0; nn < 2; ++nn)                                               \
        acc[(mb_)+mm][(nb_)+nn] = __builtin_amdgcn_mfma_i32_16x16x64_i8(                           \
            a[(mb_)+mm][kk], b[(nb_)+nn][kk], acc[(mb_)+mm][(nb_)+nn], 0, 0, 0); } while (0)

#define SP1 __builtin_amdgcn_s_setprio(1)
#define SP0 __builtin_amdgcn_s_setprio(0)
#define BAR __builtin_amdgcn_s_barrier()
#define VM(n_) asm volatile("s_waitcnt vmcnt(" #n_ ")" ::: "memory")

    int4v acc[8][4] = {};
    int4v a[8][2], b[4][2];

    // ---- prologue: buf0 <- tile0 (A,B), buf1 <- tile1 (A only); confirm buf0; read tile0 frags
    STA(0, 0, 0); STA(0, 1, 0); STB(0, 0, 0); STB(0, 1, 0);
    STA(65536, 0, 1); STA(65536, 1, 1);
    VM(4);                      // first 8 loads (buf0 A+B) landed; buf1.A (4) may be in flight
    BAR;
    LDB2(0, 0); LDA4(0, 0);     // frags for P1's MFMA

#define ITER_FULL(i_) do {                                                                         \
    const int t1 = 2*(i_)+1, t2 = 2*(i_)+2, t3 = 2*(i_)+3;                                         \
    /*P1*/ STB(65536, 0, t1); LDA4(0, 4);                  SP1; MF(0, 0); SP0;        BAR;         \
    /*P2*/ STB(65536, 1, t1); LDB2(0, 2);                  SP1; MF(4, 0); SP0;        BAR;         \
    /*P3*/ STA(0, 0, t2);                                  SP1; MF(0, 2); SP0; VM(2); BAR;         \
    /*P4*/ STA(0, 1, t2);     LDB2(65536, 0); LDA4(65536, 0); SP1; MF(4, 2); SP0;     BAR;         \
    /*P5*/ STB(0, 0, t2);     LDA4(65536, 4);              SP1; MF(0, 0); SP0;        BAR;         \
    /*P6*/ STB(0, 1, t2);     LDB2(65536, 2);              SP1; MF(4, 0); SP0;        BAR;         \
    /*P7*/ STA(65536, 0, t3);                              SP1; MF(0, 2); SP0; VM(2); BAR;         \
    /*P8*/ STA(65536, 1, t3); LDB2(0, 0); LDA4(0, 0);      SP1; MF(4, 2); SP0;        BAR;         \
} while (0)

#define ITER_TAIL() do {                                                                           \
    /*P1*/ STB(65536, 0, 31); LDA4(0, 4);                  SP1; MF(0, 0); SP0;        BAR;         \
    /*P2*/ STB(65536, 1, 31); LDB2(0, 2);                  SP1; MF(4, 0); SP0;        BAR;         \
    /*P3*/                                                 SP1; MF(0, 2); SP0; VM(0); BAR;         \
    /*P4*/ LDB2(65536, 0); LDA4(65536, 0);                 SP1; MF(4, 2); SP0;        BAR;         \
    /*P5*/ LDA4(65536, 4);                                 SP1; MF(0, 0); SP0;        BAR;         \
    /*P6*/ LDB2(65536, 2);                                 SP1; MF(4, 0); SP0;        BAR;         \
    /*P7*/                                                 SP1; MF(0, 2); SP0;        BAR;         \
    /*P8*/                                                 SP1; MF(4, 2); SP0;                     \
} while (0)

    for (int i = 0; i < NI - 1; ++i) ITER_FULL(i);
    ITER_TAIL();

#undef ITER_TAIL
#undef ITER_FULL
#undef VM
#undef BAR
#undef SP0
#undef SP1
#undef MF
#undef LDB2
#undef LDA4
#undef STB
#undef STA

    // ---- epilogue: y = clip(rint(scale[n]*(acc+bias[n]) + zp)), stored as int32 ----
    float si = p_si[0], so = p_so[0], z = p_zp[0];
    float rs = si / so;

    #pragma unroll
    for (int n = 0; n < 4; ++n) {
        int col = bn * BN + wc * 64 + n * 16 + lr;
        float sc = wscale[col] * rs;
        int   bs = bias[col];
        #pragma unroll
        for (int m = 0; m < 8; ++m) {
            int row = bm * BM + wr * 128 + m * 16 + lg * 4;
            #pragma unroll
            for (int r = 0; r < 4; ++r) {
                float y = sc * (float)(acc[m][n][r] + bs) + z;
                y = rintf(y);
                y = fminf(fmaxf(y, -128.0f), 127.0f);
                C[(size_t)(row + r) * N + col] = (int)y;
            }
        }
    }
}

// ---------------- fallback if workspace too small: naive but exact ----------------
__global__ void qgemm_naive(const int* __restrict__ qx, const int* __restrict__ qw,
                            const int* __restrict__ bias, const float* __restrict__ wscale,
                            const float* __restrict__ si, const float* __restrict__ so,
                            const float* __restrict__ zp, int* __restrict__ out) {
    int idx = blockIdx.x * blockDim.x + threadIdx.x;
    if (idx >= TOKENS * OUT_F) return;
    int row = idx / OUT_F, col = idx - row * OUT_F;
    const int4v* xa = (const int4v*)(qx + (size_t)row * IN_F);
    const int4v* wb = (const int4v*)(qw + (size_t)col * IN_F);
    int acc = 0;
    for (int k = 0; k < IN_F / 4; ++k) {
        int4v a = xa[k], b = wb[k];
        acc += a.x * b.x + a.y * b.y + a.z * b.z + a.w * b.w;
    }
    float y = wscale[col] * si[0] / so[0] * (float)(acc + bias[col]) + zp[0];
    y = fminf(fmaxf(rintf(y), -128.0f), 127.0f);
    out[idx] = (int)y;
}

extern "C" void kernel_launch(void* const* d_in, const int* in_sizes, int n_in,
                              void* d_out, int out_size, void* d_ws, size_t ws_size,
                              hipStream_t stream) {
    const int*   q_x    = (const int*)d_in[0];
    const int*   q_w    = (const int*)d_in[1];
    const int*   bias   = (const int*)d_in[2];
    const float* wscale = (const float*)d_in[3];
    const float* s_in   = (const float*)d_in[4];
    const float* s_out  = (const float*)d_in[5];
    const float* zp     = (const float*)d_in[6];
    int* out = (int*)d_out;

    const size_t needA = (size_t)TOKENS * IN_F;  // 32 MiB
    const size_t needB = (size_t)OUT_F * IN_F;   // 16 MiB

    if (ws_size >= needA + needB) {
        signed char* pA = (signed char*)d_ws;
        signed char* pB = pA + needA;
        pack_i32_to_i8<<<2048, 256, 0, stream>>>(q_x, (int*)pA, (int)(needA / 4));
        pack_i32_to_i8<<<1024, 256, 0, stream>>>(q_w, (int*)pB, (int)(needB / 4));
        int grid = (TOKENS / BM) * (OUT_F / BN);  // 32*16 = 512
        qgemm_i8<<<grid, 512, 0, stream>>>(pA, pB, bias, wscale, s_in, s_out, zp, out);
    } else {
        int total = TOKENS * OUT_F;
        qgemm_naive<<<(total + 255) / 256, 256, 0, stream>>>(q_x, q_w, bias, wscale, s_in, s_out, zp, out);
    }
}

// Round 8
// 180.394 us; speedup vs baseline: 1.2534x; 1.0065x over previous
//
#include <hip/hip_runtime.h>

#define TOKENS 8192
#define IN_F   4096
#define OUT_F  4096

#define BM 256
#define BN 256
#define BKB 128              // K-bytes per tile (= 2 mfma K-steps of 64)
#define NT (IN_F / BKB)      // 32 K-tiles
#define NI (NT / 2)          // 16 outer iterations (2 tiles each)

using int4v = __attribute__((ext_vector_type(4))) int;
typedef __attribute__((address_space(3))) char       lds_char_t;
typedef const __attribute__((address_space(1))) char glob_char_t;

// ---------------- pack int32 -> int8 (values already in [-128,127]) ----------------
__global__ void pack_i32_to_i8(const int* __restrict__ src, int* __restrict__ dst, int n4) {
    int stride = gridDim.x * blockDim.x;
    for (int i = blockIdx.x * blockDim.x + threadIdx.x; i < n4; i += stride) {
        int4v v = ((const int4v*)src)[i];
        dst[i] = (v.x & 0xff) | ((v.y & 0xff) << 8) | ((v.z & 0xff) << 16) | (v.w << 24);
    }
}

// ---------------- 256x256 i8 GEMM, 8-phase pipelined, asm-pinned ds_reads ----------------
// vs R7: fragment loads are inline-asm ds_read_b128 (issue position PINNED — the
// C++ reads were being sunk to their consumers by the scheduler, serializing
// reads+MFMA at ~1300cy/phase). Counted lgkmcnt(N) per phase, N = reads just
// issued this phase (in-order DS returns => older phase's operand reads landed),
// then sched_barrier(0) so MFMAs cannot hoist above the wait (rule #18).
// Staging schedule / vmcnt(2) confirmations / region lifetimes identical to R7
// (verified): buf1 tile 2i+1 confirmed end-P3, buf0 tile 2i+2 confirmed end-P7.
__global__ __launch_bounds__(512, 2) void qgemm_i8(
    const signed char* __restrict__ A,   // [M][K] int8
    const signed char* __restrict__ Bw,  // [N][K] int8
    const int*   __restrict__ bias,
    const float* __restrict__ wscale,
    const float* __restrict__ p_si, const float* __restrict__ p_so, const float* __restrict__ p_zp,
    int* __restrict__ C)
{
    constexpr int N = OUT_F, K = IN_F;
    constexpr int NBN = N / BN;  // 16

    __shared__ __align__(16) signed char smem[131072];

    // XCD-aware swizzle (nwg = 512, %8 == 0 -> bijective)
    int nwg = gridDim.x, bid = blockIdx.x, swz = bid;
    if ((nwg & 7) == 0) { int cpx = nwg >> 3; swz = (bid & 7) * cpx + (bid >> 3); }
    int bm = swz / NBN, bn = swz - bm * NBN;

    const int t = threadIdx.x, wid = t >> 6, l = t & 63;
    const int wr = wid >> 2, wc = wid & 3, lr = l & 15, lg = l >> 4;

    // ds_read offsets: frag (row, kk): byte = row*128 + ((kk*4+lg)^(lr&7))<<4
    const int k0off = ((lg       ^ (lr & 7)) << 4);
    const int k1off = (((4 + lg) ^ (lr & 7)) << 4);
    const int arow = (wr * 128 + lr) * 128;  // + m*2048
    const int brow = (wc * 64  + lr) * 128;  // + n*2048

    // staging: thread t writes LDS-linear o = e*8192 + t*16 within a half-tile
    // (row = e*64 + t>>3, col16 = t&7); inverse-swizzled global column:
    const int srow = t >> 3;                                  // 0..63
    const int scol = (((t & 7) ^ ((t >> 3) & 7)) << 4);
    const signed char* gApl = A  + (size_t)(bm * BM + srow) * K + scol;
    const signed char* gBpl = Bw + (size_t)(bn * BN + srow) * K + scol;

#define STA(bufOff_, h_, tt_) do {                                                                 \
    __builtin_amdgcn_global_load_lds((glob_char_t*)(gApl + (size_t)((h_)*128      ) * K + (tt_)*BKB), \
        (lds_char_t*)smem + (bufOff_) + (h_)*16384 +        wid*1024, 16, 0, 0);                   \
    __builtin_amdgcn_global_load_lds((glob_char_t*)(gApl + (size_t)((h_)*128 + 64 ) * K + (tt_)*BKB), \
        (lds_char_t*)smem + (bufOff_) + (h_)*16384 + 8192 + wid*1024, 16, 0, 0);                   \
} while (0)
#define STB(bufOff_, h_, tt_) do {                                                                 \
    __builtin_amdgcn_global_load_lds((glob_char_t*)(gBpl + (size_t)((h_)*128      ) * K + (tt_)*BKB), \
        (lds_char_t*)smem + (bufOff_) + 32768 + (h_)*16384 +        wid*1024, 16, 0, 0);           \
    __builtin_amdgcn_global_load_lds((glob_char_t*)(gBpl + (size_t)((h_)*128 + 64 ) * K + (tt_)*BKB), \
        (lds_char_t*)smem + (bufOff_) + 32768 + (h_)*16384 + 8192 + wid*1024, 16, 0, 0);           \
} while (0)

    // LDS byte-offset bases (32-bit AS(3) addresses) — swizzle folded in
#define LDSOFF(x_) ((unsigned)(uintptr_t)((lds_char_t*)smem + (x_)))
    const unsigned aB0k0 = LDSOFF(arow + k0off);
    const unsigned aB0k1 = LDSOFF(arow + k1off);
    const unsigned aB1k0 = aB0k0 + 65536u;
    const unsigned aB1k1 = aB0k1 + 65536u;
    const unsigned bB0k0 = LDSOFF(32768 + brow + k0off);
    const unsigned bB0k1 = LDSOFF(32768 + brow + k1off);
    const unsigned bB1k0 = bB0k0 + 65536u;
    const unsigned bB1k1 = bB0k1 + 65536u;

#define DSR(dst_, base_, imm_) \
    asm volatile("ds_read_b128 %0, %1 offset:" #imm_ : "=&v"(dst_) : "v"(base_))

#define RD_A_LO(p0_, p1_) do { \
    DSR(a[0][0], p0_, 0);     DSR(a[0][1], p1_, 0);     \
    DSR(a[1][0], p0_, 2048);  DSR(a[1][1], p1_, 2048);  \
    DSR(a[2][0], p0_, 4096);  DSR(a[2][1], p1_, 4096);  \
    DSR(a[3][0], p0_, 6144);  DSR(a[3][1], p1_, 6144);  } while (0)
#define RD_A_HI(p0_, p1_) do { \
    DSR(a[4][0], p0_, 8192);  DSR(a[4][1], p1_, 8192);  \
    DSR(a[5][0], p0_, 10240); DSR(a[5][1], p1_, 10240); \
    DSR(a[6][0], p0_, 12288); DSR(a[6][1], p1_, 12288); \
    DSR(a[7][0], p0_, 14336); DSR(a[7][1], p1_, 14336); } while (0)
#define RD_B_LO(p0_, p1_) do { \
    DSR(b[0][0], p0_, 0);     DSR(b[0][1], p1_, 0);     \
    DSR(b[1][0], p0_, 2048);  DSR(b[1][1], p1_, 2048);  } while (0)
#define RD_B_HI(p0_, p1_) do { \
    DSR(b[2][0], p0_, 4096);  DSR(b[2][1], p1_, 4096);  \
    DSR(b[3][0], p0_, 6144);  DSR(b[3][1], p1_, 6144);  } while (0)

#define MF(mb_, nb_) do { _Pragma("unroll") for (int kk = 0; kk < 2; ++kk)                         \
    _Pragma("unroll") for (int mm = 0; mm < 4; ++mm)                                               \
    _Pragma("unroll") for (int nn = 0; nn < 2; ++nn)                                               \
        acc[(mb_)+mm][(nb_)+nn] = __builtin_amdgcn_mfma_i32_16x16x64_i8(                           \
            a[(mb_)+mm][kk], b[(nb_)+nn][kk], acc[(mb_)+mm][(nb_)+nn], 0, 0, 0); } while (0)

#define SP1 __builtin_amdgcn_s_setprio(1)
#define SP0 __builtin_amdgcn_s_setprio(0)
#define BAR __builtin_amdgcn_s_barrier()
#define VM(n_) asm volatile("s_waitcnt vmcnt(" #n_ ")" ::: "memory")
// counted lgkm wait + fence so MFMAs cannot hoist above it (rule #18)
#define WK(n_) do { asm volatile("s_waitcnt lgkmcnt(" #n_ ")" ::: "memory"); \
                    __builtin_amdgcn_sched_barrier(0); } while (0)

    int4v acc[8][4] = {};
    int4v a[8][2], b[4][2];

    // ---- prologue: buf0 <- tile0 (A,B), buf1 <- tile1 (A only); confirm buf0; read tile0 frags
    STA(0, 0, 0); STA(0, 1, 0); STB(0, 0, 0); STB(0, 1, 0);
    STA(65536, 0, 1); STA(65536, 1, 1);
    VM(4);                      // first 8 loads (buf0 A+B) landed; buf1.A (4) may be in flight
    BAR;
    RD_B_LO(bB0k0, bB0k1); RD_A_LO(aB0k0, aB0k1);   // 12 reads feeding P1

#define ITER_FULL(i_) do {                                                                         \
    const int t1 = 2*(i_)+1, t2 = 2*(i_)+2, t3 = 2*(i_)+3;                                         \
    /*P1*/ STB(65536, 0, t1); RD_A_HI(aB0k0, aB0k1);                WK(8);  SP1; MF(0, 0); SP0;        BAR; \
    /*P2*/ STB(65536, 1, t1); RD_B_HI(bB0k0, bB0k1);                WK(4);  SP1; MF(4, 0); SP0;        BAR; \
    /*P3*/ STA(0, 0, t2);                                           WK(0);  SP1; MF(0, 2); SP0; VM(2); BAR; \
    /*P4*/ STA(0, 1, t2); RD_B_LO(bB1k0, bB1k1); RD_A_LO(aB1k0, aB1k1); WK(12); SP1; MF(4, 2); SP0;    BAR; \
    /*P5*/ STB(0, 0, t2); RD_A_HI(aB1k0, aB1k1);                    WK(8);  SP1; MF(0, 0); SP0;        BAR; \
    /*P6*/ STB(0, 1, t2); RD_B_HI(bB1k0, bB1k1);                    WK(4);  SP1; MF(4, 0); SP0;        BAR; \
    /*P7*/ STA(65536, 0, t3);                                       WK(0);  SP1; MF(0, 2); SP0; VM(2); BAR; \
    /*P8*/ STA(65536, 1, t3); RD_B_LO(bB0k0, bB0k1); RD_A_LO(aB0k0, aB0k1); WK(12); SP1; MF(4, 2); SP0; BAR; \
} while (0)

#define ITER_TAIL() do {                                                                           \
    /*P1*/ STB(65536, 0, 31); RD_A_HI(aB0k0, aB0k1);                WK(8);  SP1; MF(0, 0); SP0;        BAR; \
    /*P2*/ STB(65536, 1, 31); RD_B_HI(bB0k0, bB0k1);                WK(4);  SP1; MF(4, 0); SP0;        BAR; \
    /*P3*/                                                          WK(0);  SP1; MF(0, 2); SP0; VM(0); BAR; \
    /*P4*/ RD_B_LO(bB1k0, bB1k1); RD_A_LO(aB1k0, aB1k1);            WK(12); SP1; MF(4, 2); SP0;        BAR; \
    /*P5*/ RD_A_HI(aB1k0, aB1k1);                                   WK(8);  SP1; MF(0, 0); SP0;        BAR; \
    /*P6*/ RD_B_HI(bB1k0, bB1k1);                                   WK(4);  SP1; MF(4, 0); SP0;        BAR; \
    /*P7*/                                                          WK(0);  SP1; MF(0, 2); SP0;        BAR; \
    /*P8*/                                                          WK(0);  SP1; MF(4, 2); SP0;             \
} while (0)

    for (int i = 0; i < NI - 1; ++i) ITER_FULL(i);
    ITER_TAIL();

#undef ITER_TAIL
#undef ITER_FULL
#undef WK
#undef VM
#undef BAR
#undef SP0
#undef SP1
#undef MF
#undef RD_B_HI
#undef RD_B_LO
#undef RD_A_HI
#undef RD_A_LO
#undef DSR
#undef LDSOFF
#undef STB
#undef STA

    // ---- epilogue: y = clip(rint(scale[n]*(acc+bias[n]) + zp)), stored as int32 ----
    float si = p_si[0], so = p_so[0], z = p_zp[0];
    float rs = si / so;

    #pragma unroll
    for (int n = 0; n < 4; ++n) {
        int col = bn * BN + wc * 64 + n * 16 + lr;
        float sc = wscale[col] * rs;
        int   bs = bias[col];
        #pragma unroll
        for (int m = 0; m < 8; ++m) {
            int row = bm * BM + wr * 128 + m * 16 + lg * 4;
            #pragma unroll
            for (int r = 0; r < 4; ++r) {
                float y = sc * (float)(acc[m][n][r] + bs) + z;
                y = rintf(y);
                y = fminf(fmaxf(y, -128.0f), 127.0f);
                C[(size_t)(row + r) * N + col] = (int)y;
            }
        }
    }
}

// ---------------- fallback if workspace too small: naive but exact ----------------
__global__ void qgemm_naive(const int* __restrict__ qx, const int* __restrict__ qw,
                            const int* __restrict__ bias, const float* __restrict__ wscale,
                            const float* __restrict__ si, const float* __restrict__ so,
                            const float* __restrict__ zp, int* __restrict__ out) {
    int idx = blockIdx.x * blockDim.x + threadIdx.x;
    if (idx >= TOKENS * OUT_F) return;
    int row = idx / OUT_F, col = idx - row * OUT_F;
    const int4v* xa = (const int4v*)(qx + (size_t)row * IN_F);
    const int4v* wb = (const int4v*)(qw + (size_t)col * IN_F);
    int acc = 0;
    for (int k = 0; k < IN_F / 4; ++k) {
        int4v a = xa[k], b = wb[k];
        acc += a.x * b.x + a.y * b.y + a.z * b.z + a.w * b.w;
    }
    float y = wscale[col] * si[0] / so[0] * (float)(acc + bias[col]) + zp[0];
    y = fminf(fmaxf(rintf(y), -128.0f), 127.0f);
    out[idx] = (int)y;
}

extern "C" void kernel_launch(void* const* d_in, const int* in_sizes, int n_in,
                              void* d_out, int out_size, void* d_ws, size_t ws_size,
                              hipStream_t stream) {
    const int*   q_x    = (const int*)d_in[0];
    const int*   q_w    = (const int*)d_in[1];
    const int*   bias   = (const int*)d_in[2];
    const float* wscale = (const float*)d_in[3];
    const float* s_in   = (const float*)d_in[4];
    const float* s_out  = (const float*)d_in[5];
    const float* zp     = (const float*)d_in[6];
    int* out = (int*)d_out;

    const size_t needA = (size_t)TOKENS * IN_F;  // 32 MiB
    const size_t needB = (size_t)OUT_F * IN_F;   // 16 MiB

    if (ws_size >= needA + needB) {
        signed char* pA = (signed char*)d_ws;
        signed char* pB = pA + needA;
        pack_i32_to_i8<<<2048, 256, 0, stream>>>(q_x, (int*)pA, (int)(needA / 4));
        pack_i32_to_i8<<<1024, 256, 0, stream>>>(q_w, (int*)pB, (int)(needB / 4));
        int grid = (TOKENS / BM) * (OUT_F / BN);  // 32*16 = 512
        qgemm_i8<<<grid, 512, 0, stream>>>(pA, pB, bias, wscale, s_in, s_out, zp, out);
    } else {
        int total = TOKENS * OUT_F;
        qgemm_naive<<<(total + 255) / 256, 256, 0, stream>>>(q_x, q_w, bias, wscale, s_in, s_out, zp, out);
    }
}